// Round 4
// baseline (506.664 us; speedup 1.0000x reference)
//
#include <hip/hip_runtime.h>

// Problem constants
#define TT 16384
#define W_WARM 416
#define CHUNK 16
#define NSTEP (W_WARM + CHUNK)  // 432 = 3*144, divisible by 3
#define RECF 1088               // floats per per-step record
#define RECB 4352               // bytes per record

#define RL(v, m) __int_as_float(__builtin_amdgcn_readlane(__float_as_int(v), (m)))
// DPP row_ror:K within 16-lane rows: dst[i] = src[(i-K)&15] (per row).
// Direction pinned by the canonical DPP prefix-scan idiom (row_shr:k ==
// dst[i]=src[i-k]); row_ror is the wrapping variant.
#define ROR(v, K) \
    __int_as_float(__builtin_amdgcn_update_dpp(0, __float_as_int(v), 0x120 + (K), 0xF, 0xF, false))

__device__ __forceinline__ float fsig(float x) {
    return __builtin_amdgcn_rcpf(1.0f + __builtin_amdgcn_exp2f(-1.4426950408889634f * x));
}
__device__ __forceinline__ float ftanh(float x) {
    return fmaf(-2.0f, __builtin_amdgcn_rcpf(1.0f + __builtin_amdgcn_exp2f(2.8853900817779268f * x)), 1.0f);
}

// ---------------------------------------------------------------------------
// Kernel 1: fixed matrices from a_list: fix = [Lsum, M0, M1, M2]
// ---------------------------------------------------------------------------
__global__ void k_fixed(const float* __restrict__ a, float* __restrict__ fix) {
    __shared__ float Lh[3][16][16];
    __shared__ float Ls[16][16];
    __shared__ float dsh[3][16];
    int tid = threadIdx.x;
    if (tid < 48) {
        int l = tid >> 4, j = tid & 15;
        float s = 0.f;
        for (int i = 0; i < 16; i++) s += a[l * 256 + i * 16 + j];
        dsh[l][j] = s;
    }
    __syncthreads();
    int i = tid >> 4, j = tid & 15;
    for (int l = 0; l < 3; l++) {
        float L = ((i == j) ? dsh[l][i] : 0.0f) - a[l * 256 + i * 16 + j];
        Lh[l][i][j] = L * rsqrtf(dsh[l][i]) * rsqrtf(dsh[l][j]);
    }
    __syncthreads();
    float ls = Lh[0][i][j] + Lh[1][i][j] + Lh[2][i][j];
    Ls[i][j] = ls;
    fix[i * 16 + j] = ls;
    __syncthreads();
    for (int l = 0; l < 3; l++) {
        float m = 0.f;
        for (int k = 0; k < 16; k++) m += Lh[l][i][k] * Ls[k][j];
        fix[(l + 1) * 256 + i * 16 + j] = m;
    }
}

// ---------------------------------------------------------------------------
// Kernel 2: per-t record precompute; gru_k staged through LDS (coalesced).
// Record (1088 f), DIAGONAL packing per 16x16 block for the walker's DPP-rotate
// dot:  blk[n][k] = W[n][(n-k)&15]:
//   [A 256][K1^T 256][K3^T 256][K5^T 256][ex 64: per-n {bh,uR,uZ,u4}]
// ---------------------------------------------------------------------------
__global__ __launch_bounds__(128) void k_prep3(const float* __restrict__ inp,
                                               const float* __restrict__ wx_,
                                               const float* __restrict__ bx_,
                                               const float* __restrict__ wh_,
                                               const float* __restrict__ bh_,
                                               const float* __restrict__ gk,
                                               const float* __restrict__ gb,
                                               float* __restrict__ ws) {
    __shared__ float sfix[1024];
    __shared__ float srec[8][RECF];
    __shared__ float sgk[8][768];
    __shared__ float sxg[8][16];
    int tid = threadIdx.x;
    int t_base = blockIdx.x * 8;
    for (int i = tid; i < 1024; i += 128) sfix[i] = ws[i];
    // phase 1: even K matrices (K0,K2,K4) coalesced into LDS
    {
        float4* dst = (float4*)&sgk[0][0];
        const float4* src = (const float4*)gk;
        for (int i = tid; i < 1536; i += 128) {
            int tl2 = i / 192, r = i - tl2 * 192;
            int mtx = r >> 6, w = r & 63;
            dst[i] = src[(size_t)(t_base + tl2) * 384 + mtx * 128 + w];
        }
    }
    __syncthreads();
    int tl = tid >> 4, n = tid & 15;
    int t = t_base + tl;
    bool z0 = (t == 0);

    // A row n (diagonal-packed)
    const float* wh = wh_ + t * 13;
    float w0 = wh[0];
    float aI = wh[10], aL = wh[11] * w0;
    float wc = wh[12] * w0;
    float c0 = wc * w0, c1 = wc * wh[1], c2 = wc * wh[2];
    for (int m = 0; m < 16; m++) {
        float Av = aL * sfix[n * 16 + m] + c0 * sfix[256 + n * 16 + m] +
                   c1 * sfix[512 + n * 16 + m] + c2 * sfix[768 + n * 16 + m];
        if (m == n) Av += aI;
        srec[tl][n * 16 + ((n - m) & 15)] = z0 ? 0.f : Av;
    }

    // xg[n]
    float acc = bx_[t * 16 + n];
    for (int c = 0; c < 2; c++) {
        const float* wx = wx_ + t * 26 + c * 13;
        float yL = 0.f, y0 = 0.f, y1 = 0.f, y2 = 0.f;
        for (int m = 0; m < 16; m++) {
            float xm = inp[t * 32 + m * 2 + c];
            yL += sfix[n * 16 + m] * xm;
            y0 += sfix[256 + n * 16 + m] * xm;
            y1 += sfix[512 + n * 16 + m] * xm;
            y2 += sfix[768 + n * 16 + m] * xm;
        }
        float xn = inp[t * 32 + n * 2 + c];
        float b0 = wx[12] * wx[0];
        acc += wx[10] * xn + wx[11] * wx[0] * yL + b0 * (wx[0] * y0 + wx[1] * y1 + wx[2] * y2);
    }
    float xg = fmaxf(acc, 0.f);
    sxg[tl][n] = xg;
    __syncthreads();

    // u_q[n] = xg @ K_{2q} + B_{2q} + B_{2q+1}  (K from LDS)
    const float* gbt = gb + (size_t)t * 96;
    float u[3];
    for (int qq = 0; qq < 3; qq++) {
        const float* K = &sgk[tl][qq * 256];
        float s = gbt[2 * qq * 16 + n] + gbt[(2 * qq + 1) * 16 + n];
        for (int m = 0; m < 16; m++) s += sxg[tl][m] * K[m * 16 + n];
        u[qq] = s;
    }
    srec[tl][1024 + n * 4 + 0] = z0 ? 0.f : bh_[t * 16 + n];
    srec[tl][1024 + n * 4 + 1] = u[0];
    srec[tl][1024 + n * 4 + 2] = u[1];
    srec[tl][1024 + n * 4 + 3] = u[2];
    __syncthreads();
    // phase 2: odd K matrices (K1,K3,K5) coalesced into LDS (overwrite)
    {
        float4* dst = (float4*)&sgk[0][0];
        const float4* src = (const float4*)gk;
        for (int i = tid; i < 1536; i += 128) {
            int tl2 = i / 192, r = i - tl2 * 192;
            int mtx = r >> 6, w = r & 63;
            dst[i] = src[(size_t)(t_base + tl2) * 384 + mtx * 128 + 64 + w];
        }
    }
    __syncthreads();
    // transpose odd Ks (col n -> contiguous, diagonal-packed)
    for (int b = 0; b < 3; b++) {
        const float* K = &sgk[tl][b * 256];
        float* d = &srec[tl][256 * (b + 1)];
        for (int m = 0; m < 16; m++)
            d[n * 16 + ((n - m) & 15)] = K[m * 16 + n];
    }
    __syncthreads();
    // coalesced stream-out
    float4* gdst = (float4*)(ws + 1024 + (size_t)t_base * RECF);
    const float4* lsrc = (const float4*)&srec[0][0];
    for (int i = tid; i < 8 * RECF / 4; i += 128) gdst[i] = lsrc[i];
}

// ---------------------------------------------------------------------------
// Kernel 3: walker v6. FOUR independent chains per wave, one per 16-lane DPP
// row. Lane n holds h[n]; every gate value is lane-local; the only cross-lane
// ops are row-confined row_ror rotations. No LDS, no DS pipe, no permlane.
// ---------------------------------------------------------------------------
struct Slot {
    float4 A0, A1, A2, A3;  // A (diag-packed row n)
    float4 B0, B1, B2, B3;  // K1^T (r gate)
    float4 Z0, Z1, Z2, Z3;  // K3^T (z gate)
    float4 C0, C1, C2, C3;  // K5^T (candidate)
    float4 ex;              // {bh, uR, uZ, u4}
};

__device__ __forceinline__ void rot16(float v, float rr[16]) {
    rr[0] = v;
    rr[1] = ROR(v, 1);
    rr[2] = ROR(v, 2);
    rr[3] = ROR(v, 3);
    rr[4] = ROR(v, 4);
    rr[5] = ROR(v, 5);
    rr[6] = ROR(v, 6);
    rr[7] = ROR(v, 7);
    rr[8] = ROR(v, 8);
    rr[9] = ROR(v, 9);
    rr[10] = ROR(v, 10);
    rr[11] = ROR(v, 11);
    rr[12] = ROR(v, 12);
    rr[13] = ROR(v, 13);
    rr[14] = ROR(v, 14);
    rr[15] = ROR(v, 15);
}

__device__ __forceinline__ float dotw(const float4& w0, const float4& w1, const float4& w2,
                                      const float4& w3, const float rr[16]) {
    float a0 = w0.x * rr[0];
    float a1 = w0.y * rr[1];
    float a2 = w0.z * rr[2];
    float a3 = w0.w * rr[3];
    a0 = fmaf(w1.x, rr[4], a0);
    a1 = fmaf(w1.y, rr[5], a1);
    a2 = fmaf(w1.z, rr[6], a2);
    a3 = fmaf(w1.w, rr[7], a3);
    a0 = fmaf(w2.x, rr[8], a0);
    a1 = fmaf(w2.y, rr[9], a1);
    a2 = fmaf(w2.z, rr[10], a2);
    a3 = fmaf(w2.w, rr[11], a3);
    a0 = fmaf(w3.x, rr[12], a0);
    a1 = fmaf(w3.y, rr[13], a1);
    a2 = fmaf(w3.z, rr[14], a2);
    a3 = fmaf(w3.w, rr[15], a3);
    return (a0 + a1) + (a2 + a3);
}

__device__ __forceinline__ void load_slot(Slot& S, const char* __restrict__ recb8, int t,
                                          unsigned offA, unsigned offX) {
    const char* r = recb8 + (size_t)t * RECB;
    S.A0 = *(const float4*)(r + offA);
    S.A1 = *(const float4*)(r + offA + 16);
    S.A2 = *(const float4*)(r + offA + 32);
    S.A3 = *(const float4*)(r + offA + 48);
    S.B0 = *(const float4*)(r + offA + 1024);
    S.B1 = *(const float4*)(r + offA + 1040);
    S.B2 = *(const float4*)(r + offA + 1056);
    S.B3 = *(const float4*)(r + offA + 1072);
    S.Z0 = *(const float4*)(r + offA + 2048);
    S.Z1 = *(const float4*)(r + offA + 2064);
    S.Z2 = *(const float4*)(r + offA + 2080);
    S.Z3 = *(const float4*)(r + offA + 2096);
    S.C0 = *(const float4*)(r + offA + 3072);
    S.C1 = *(const float4*)(r + offA + 3088);
    S.C2 = *(const float4*)(r + offA + 3104);
    S.C3 = *(const float4*)(r + offA + 3120);
    S.ex = *(const float4*)(r + offX);
}

__device__ __forceinline__ float wstep6(const Slot& S, float hv, int t, int t0, int n,
                                        float* __restrict__ out) {
    // hg = relu(A h + bh): lane n computes row n via rotations of hv.
    float hh[16];
    rot16(hv, hh);
    float hg = fmaxf(dotw(S.A0, S.A1, S.A2, S.A3, hh) + S.ex.x, 0.f);
    // r and z share the rotations of hg.
    float hgr[16];
    rot16(hg, hgr);
    float r = fsig(dotw(S.B0, S.B1, S.B2, S.B3, hgr) + S.ex.y);
    float z = fsig(dotw(S.Z0, S.Z1, S.Z2, S.Z3, hgr) + S.ex.z);
    float rg[16];
    rot16(r * hg, rg);
    float hc = ftanh(dotw(S.C0, S.C1, S.C2, S.C3, rg) + S.ex.w);
    float hn = fmaf(z, hg - hc, hc);  // h' = hc + z*(hg - hc), all lane-local
    if ((unsigned)(t - t0) < (unsigned)CHUNK) out[(size_t)t * 16 + n] = hn;
    return hn;
}

__global__ __launch_bounds__(64, 1) void k_walk6(const float* __restrict__ ws,
                                                 float* __restrict__ out) {
    const char* recb8 = (const char*)(ws + 1024);
    int lane = threadIdx.x;
    int n = lane & 15;
    int row = lane >> 4;  // chain within wave (0..3), one per DPP row

    unsigned offA = n * 64;
    unsigned offX = 4096 + n * 16;

    // XCD grouping: blocks b with equal (b&7) land on one XCD; give them
    // consecutive logical indices so overlapping warm windows share L2.
    int b = blockIdx.x;
    int L = (b & 7) * 32 + (b >> 3);
    int t0 = (L * 4 + row) * CHUNK;  // this row's chunk start
    int ts = t0 - W_WARM;
    if (ts < 0) ts = 0;
    int tend = t0 + CHUNK - 1;

    float hv = 0.f;

    Slot R0, R1, R2;
    load_slot(R0, recb8, ts + 0, offA, offX);
    load_slot(R1, recb8, ts + 1, offA, offX);
    load_slot(R2, recb8, ts + 2, offA, offX);

    for (int s = 0; s < NSTEP; s += 3) {
        int t = ts + s;
        int tl;
        hv = wstep6(R0, hv, t + 0, t0, n, out);
        tl = t + 3;
        if (tl > tend) tl = tend;
        load_slot(R0, recb8, tl, offA, offX);
        hv = wstep6(R1, hv, t + 1, t0, n, out);
        tl = t + 4;
        if (tl > tend) tl = tend;
        load_slot(R1, recb8, tl, offA, offX);
        hv = wstep6(R2, hv, t + 2, t0, n, out);
        tl = t + 5;
        if (tl > tend) tl = tend;
        load_slot(R2, recb8, tl, offA, offX);
    }
}

// ---------------------------------------------------------------------------
// Fallback (compact records) if ws is too small
// ---------------------------------------------------------------------------
__global__ void k_prep_c(const float* __restrict__ inp, const float* __restrict__ wx_,
                         const float* __restrict__ bx_, const float* __restrict__ wh_,
                         const float* __restrict__ bh_, const float* __restrict__ gk,
                         const float* __restrict__ gb, float* __restrict__ ws) {
    __shared__ float sfix[1024];
    __shared__ float sxg[16][16];
    int tid = threadIdx.x;
    for (int idx = tid; idx < 1024; idx += 256) sfix[idx] = ws[idx];
    int tl = tid >> 4, n = tid & 15;
    int t = blockIdx.x * 16 + tl;
    __syncthreads();
    float* rec = ws + 1024 + (size_t)t * 320;
    bool z0 = (t == 0);
    const float* wh = wh_ + t * 13;
    float w0 = wh[0];
    float aI = wh[10], aL = wh[11] * w0;
    float wc = wh[12] * w0;
    float c0 = wc * w0, c1 = wc * wh[1], c2 = wc * wh[2];
    for (int m = 0; m < 16; m++) {
        float Av = aL * sfix[n * 16 + m] + c0 * sfix[256 + n * 16 + m] +
                   c1 * sfix[512 + n * 16 + m] + c2 * sfix[768 + n * 16 + m];
        if (m == n) Av += aI;
        rec[n * 16 + m] = z0 ? 0.f : Av;
    }
    float acc = bx_[t * 16 + n];
    for (int c = 0; c < 2; c++) {
        const float* wx = wx_ + t * 26 + c * 13;
        float yL = 0.f, y0 = 0.f, y1 = 0.f, y2 = 0.f;
        for (int m = 0; m < 16; m++) {
            float xm = inp[t * 32 + m * 2 + c];
            yL += sfix[n * 16 + m] * xm;
            y0 += sfix[256 + n * 16 + m] * xm;
            y1 += sfix[512 + n * 16 + m] * xm;
            y2 += sfix[768 + n * 16 + m] * xm;
        }
        float xn = inp[t * 32 + n * 2 + c];
        float b0 = wx[12] * wx[0];
        acc += wx[10] * xn + wx[11] * wx[0] * yL + b0 * (wx[0] * y0 + wx[1] * y1 + wx[2] * y2);
    }
    float xg = fmaxf(acc, 0.f);
    sxg[tl][n] = xg;
    __syncthreads();
    const float* Kb = gk + (size_t)t * 1536;
    const float* gbt = gb + (size_t)t * 96;
    for (int qq = 0; qq < 3; qq++) {
        const float* K = Kb + (2 * qq) * 256;
        float u = gbt[2 * qq * 16 + n] + gbt[(2 * qq + 1) * 16 + n];
        for (int m = 0; m < 16; m++) u += sxg[tl][m] * K[m * 16 + n];
        rec[256 + qq * 16 + n] = u;
    }
    rec[304 + n] = z0 ? 0.f : bh_[t * 16 + n];
}

struct RegsC {
    float WA[16], WB[16], WC[16];
    float uRZ, u4, bh;
};

__device__ __forceinline__ void load_step_c(const float* __restrict__ recb,
                                            const float* __restrict__ gk, int t, int n, int q,
                                            RegsC& R) {
    const float* rb = recb + (size_t)t * 320;
#pragma unroll
    for (int k = 0; k < 4; k++) ((float4*)R.WA)[k] = ((const float4*)(rb + n * 16))[k];
    const float* kb = gk + (size_t)t * 1536 + (1 + 2 * (q & 1)) * 256 + n;
    const float* kc = gk + (size_t)t * 1536 + 5 * 256 + n;
#pragma unroll
    for (int m = 0; m < 16; m++) {
        R.WB[m] = kb[m * 16];
        R.WC[m] = kc[m * 16];
    }
    R.uRZ = rb[256 + (q & 1) * 16 + n];
    R.u4 = rb[288 + n];
    R.bh = rb[304 + n];
}

__device__ __forceinline__ void wstep_c(const RegsC& R, float hs[16], int t, int t0, int lane,
                                        int n, float* __restrict__ out) {
    float a0 = 0.f, a1 = 0.f, a2 = 0.f, a3 = 0.f;
#pragma unroll
    for (int m = 0; m < 16; m += 4) {
        a0 = fmaf(R.WA[m + 0], hs[m + 0], a0);
        a1 = fmaf(R.WA[m + 1], hs[m + 1], a1);
        a2 = fmaf(R.WA[m + 2], hs[m + 2], a2);
        a3 = fmaf(R.WA[m + 3], hs[m + 3], a3);
    }
    float hg = fmaxf((a0 + a1) + (a2 + a3) + R.bh, 0.f);
    float hgs[16];
#pragma unroll
    for (int m = 0; m < 16; m++) hgs[m] = RL(hg, m);
    a0 = a1 = a2 = a3 = 0.f;
#pragma unroll
    for (int m = 0; m < 16; m += 4) {
        a0 = fmaf(R.WB[m + 0], hgs[m + 0], a0);
        a1 = fmaf(R.WB[m + 1], hgs[m + 1], a1);
        a2 = fmaf(R.WB[m + 2], hgs[m + 2], a2);
        a3 = fmaf(R.WB[m + 3], hgs[m + 3], a3);
    }
    float rz = fsig((a0 + a1) + (a2 + a3) + R.uRZ);
    float zsw = __shfl_xor(rz, 16);
    float rhg = rz * hg;
    float rhgs[16];
#pragma unroll
    for (int m = 0; m < 16; m++) rhgs[m] = RL(rhg, m);
    a0 = a1 = a2 = a3 = 0.f;
#pragma unroll
    for (int m = 0; m < 16; m += 4) {
        a0 = fmaf(R.WC[m + 0], rhgs[m + 0], a0);
        a1 = fmaf(R.WC[m + 1], rhgs[m + 1], a1);
        a2 = fmaf(R.WC[m + 2], rhgs[m + 2], a2);
        a3 = fmaf(R.WC[m + 3], rhgs[m + 3], a3);
    }
    float hc = ftanh((a0 + a1) + (a2 + a3) + R.u4);
    float h = fmaf(zsw, hg - hc, hc);
    if (t >= t0 && lane < 16) out[(size_t)t * 16 + n] = h;
#pragma unroll
    for (int m = 0; m < 16; m++) hs[m] = RL(h, m);
}

__global__ __launch_bounds__(64) void k_walk_c(const float* __restrict__ ws,
                                               const float* __restrict__ gk,
                                               float* __restrict__ out) {
    const float* recb = ws + 1024;
    int lane = threadIdx.x;
    int n = lane & 15;
    int q = lane >> 4;
    int t0 = blockIdx.x * 64;
    int te = t0 + 64;
    int ts = t0 - W_WARM;
    if (ts < 0) ts = 0;
    RegsC Ra, Rb;
    load_step_c(recb, gk, ts, n, q, Ra);
    load_step_c(recb, gk, ts + 1, n, q, Rb);
    float hs[16];
#pragma unroll
    for (int m = 0; m < 16; m++) hs[m] = 0.f;
    for (int t = ts; t < te; t += 2) {
        wstep_c(Ra, hs, t, t0, lane, n, out);
        int tn = t + 2;
        load_step_c(recb, gk, tn < TT ? tn : TT - 1, n, q, Ra);
        wstep_c(Rb, hs, t + 1, t0, lane, n, out);
        int tm = t + 3;
        load_step_c(recb, gk, tm < TT ? tm : TT - 1, n, q, Rb);
    }
}

// ---------------------------------------------------------------------------
extern "C" void kernel_launch(void* const* d_in, const int* in_sizes, int n_in, void* d_out,
                              int out_size, void* d_ws, size_t ws_size, hipStream_t stream) {
    const float* inp = (const float*)d_in[0];
    const float* a = (const float*)d_in[1];
    const float* wx = (const float*)d_in[2];
    const float* bx = (const float*)d_in[3];
    const float* wh = (const float*)d_in[4];
    const float* bh = (const float*)d_in[5];
    const float* gk = (const float*)d_in[6];
    const float* gb = (const float*)d_in[7];
    float* out = (float*)d_out;
    float* ws = (float*)d_ws;

    size_t need = 4ull * (1024ull + (size_t)TT * RECF);  // ~71.3 MB
    k_fixed<<<dim3(1), dim3(256), 0, stream>>>(a, ws);
    if (ws_size >= need) {
        k_prep3<<<dim3(TT / 8), dim3(128), 0, stream>>>(inp, wx, bx, wh, bh, gk, gb, ws);
        k_walk6<<<dim3(TT / (4 * CHUNK)), dim3(64), 0, stream>>>(ws, out);
    } else {
        k_prep_c<<<dim3(TT / 16), dim3(256), 0, stream>>>(inp, wx, bx, wh, bh, gk, gb, ws);
        k_walk_c<<<dim3(TT / 64), dim3(64), 0, stream>>>(ws, gk, out);
    }
}

// Round 7
// 414.372 us; speedup vs baseline: 1.2227x; 1.2227x over previous
//
#include <hip/hip_runtime.h>

// Problem constants
#define TT 16384
#define W_WARM 416
#define CHUNK 32
#define NSTEP (W_WARM + CHUNK)  // 448 (loop overruns to 450 harmlessly; stores are range-gated)
#define RECF 1088               // floats per per-step record
#define RECB 4352               // bytes per record

#define RL(v, m) __int_as_float(__builtin_amdgcn_readlane(__float_as_int(v), (m)))
// DPP row_ror:K within 16-lane rows: dst[i] = src[(i-K)&15] (per row).
#define ROR(v, K) \
    __int_as_float(__builtin_amdgcn_update_dpp(0, __float_as_int(v), 0x120 + (K), 0xF, 0xF, false))

__device__ __forceinline__ float fsig(float x) {
    return __builtin_amdgcn_rcpf(1.0f + __builtin_amdgcn_exp2f(-1.4426950408889634f * x));
}
__device__ __forceinline__ float ftanh(float x) {
    return fmaf(-2.0f, __builtin_amdgcn_rcpf(1.0f + __builtin_amdgcn_exp2f(2.8853900817779268f * x)), 1.0f);
}

// ---------------------------------------------------------------------------
// Kernel 1: fixed matrices from a_list: fix = [Lsum, M0, M1, M2]
// ---------------------------------------------------------------------------
__global__ void k_fixed(const float* __restrict__ a, float* __restrict__ fix) {
    __shared__ float Lh[3][16][16];
    __shared__ float Ls[16][16];
    __shared__ float dsh[3][16];
    int tid = threadIdx.x;
    if (tid < 48) {
        int l = tid >> 4, j = tid & 15;
        float s = 0.f;
        for (int i = 0; i < 16; i++) s += a[l * 256 + i * 16 + j];
        dsh[l][j] = s;
    }
    __syncthreads();
    int i = tid >> 4, j = tid & 15;
    for (int l = 0; l < 3; l++) {
        float L = ((i == j) ? dsh[l][i] : 0.0f) - a[l * 256 + i * 16 + j];
        Lh[l][i][j] = L * rsqrtf(dsh[l][i]) * rsqrtf(dsh[l][j]);
    }
    __syncthreads();
    float ls = Lh[0][i][j] + Lh[1][i][j] + Lh[2][i][j];
    Ls[i][j] = ls;
    fix[i * 16 + j] = ls;
    __syncthreads();
    for (int l = 0; l < 3; l++) {
        float m = 0.f;
        for (int k = 0; k < 16; k++) m += Lh[l][i][k] * Ls[k][j];
        fix[(l + 1) * 256 + i * 16 + j] = m;
    }
}

// ---------------------------------------------------------------------------
// Kernel 2: per-t record precompute; gru_k staged through LDS (coalesced).
// Record (1088 f), DIAGONAL packing per 16x16 block for the walker's DPP-rotate
// dot:  blk[n][k] = W[n][(n-k)&15]:
//   [A 256][K1^T 256][K3^T 256][K5^T 256][ex 64: per-n {bh,uR,uZ,u4}]
// ---------------------------------------------------------------------------
__global__ __launch_bounds__(128) void k_prep3(const float* __restrict__ inp,
                                               const float* __restrict__ wx_,
                                               const float* __restrict__ bx_,
                                               const float* __restrict__ wh_,
                                               const float* __restrict__ bh_,
                                               const float* __restrict__ gk,
                                               const float* __restrict__ gb,
                                               float* __restrict__ ws) {
    __shared__ float sfix[1024];
    __shared__ float srec[8][RECF];
    __shared__ float sgk[8][768];
    __shared__ float sxg[8][16];
    int tid = threadIdx.x;
    int t_base = blockIdx.x * 8;
    for (int i = tid; i < 1024; i += 128) sfix[i] = ws[i];
    // phase 1: even K matrices (K0,K2,K4) coalesced into LDS
    {
        float4* dst = (float4*)&sgk[0][0];
        const float4* src = (const float4*)gk;
        for (int i = tid; i < 1536; i += 128) {
            int tl2 = i / 192, r = i - tl2 * 192;
            int mtx = r >> 6, w = r & 63;
            dst[i] = src[(size_t)(t_base + tl2) * 384 + mtx * 128 + w];
        }
    }
    __syncthreads();
    int tl = tid >> 4, n = tid & 15;
    int t = t_base + tl;
    bool z0 = (t == 0);

    // A row n (diagonal-packed)
    const float* wh = wh_ + t * 13;
    float w0 = wh[0];
    float aI = wh[10], aL = wh[11] * w0;
    float wc = wh[12] * w0;
    float c0 = wc * w0, c1 = wc * wh[1], c2 = wc * wh[2];
    for (int m = 0; m < 16; m++) {
        float Av = aL * sfix[n * 16 + m] + c0 * sfix[256 + n * 16 + m] +
                   c1 * sfix[512 + n * 16 + m] + c2 * sfix[768 + n * 16 + m];
        if (m == n) Av += aI;
        srec[tl][n * 16 + ((n - m) & 15)] = z0 ? 0.f : Av;
    }

    // xg[n]
    float acc = bx_[t * 16 + n];
    for (int c = 0; c < 2; c++) {
        const float* wx = wx_ + t * 26 + c * 13;
        float yL = 0.f, y0 = 0.f, y1 = 0.f, y2 = 0.f;
        for (int m = 0; m < 16; m++) {
            float xm = inp[t * 32 + m * 2 + c];
            yL += sfix[n * 16 + m] * xm;
            y0 += sfix[256 + n * 16 + m] * xm;
            y1 += sfix[512 + n * 16 + m] * xm;
            y2 += sfix[768 + n * 16 + m] * xm;
        }
        float xn = inp[t * 32 + n * 2 + c];
        float b0 = wx[12] * wx[0];
        acc += wx[10] * xn + wx[11] * wx[0] * yL + b0 * (wx[0] * y0 + wx[1] * y1 + wx[2] * y2);
    }
    float xg = fmaxf(acc, 0.f);
    sxg[tl][n] = xg;
    __syncthreads();

    // u_q[n] = xg @ K_{2q} + B_{2q} + B_{2q+1}  (K from LDS)
    const float* gbt = gb + (size_t)t * 96;
    float u[3];
    for (int qq = 0; qq < 3; qq++) {
        const float* K = &sgk[tl][qq * 256];
        float s = gbt[2 * qq * 16 + n] + gbt[(2 * qq + 1) * 16 + n];
        for (int m = 0; m < 16; m++) s += sxg[tl][m] * K[m * 16 + n];
        u[qq] = s;
    }
    srec[tl][1024 + n * 4 + 0] = z0 ? 0.f : bh_[t * 16 + n];
    srec[tl][1024 + n * 4 + 1] = u[0];
    srec[tl][1024 + n * 4 + 2] = u[1];
    srec[tl][1024 + n * 4 + 3] = u[2];
    __syncthreads();
    // phase 2: odd K matrices (K1,K3,K5) coalesced into LDS (overwrite)
    {
        float4* dst = (float4*)&sgk[0][0];
        const float4* src = (const float4*)gk;
        for (int i = tid; i < 1536; i += 128) {
            int tl2 = i / 192, r = i - tl2 * 192;
            int mtx = r >> 6, w = r & 63;
            dst[i] = src[(size_t)(t_base + tl2) * 384 + mtx * 128 + 64 + w];
        }
    }
    __syncthreads();
    // transpose odd Ks (col n -> contiguous, diagonal-packed)
    for (int b = 0; b < 3; b++) {
        const float* K = &sgk[tl][b * 256];
        float* d = &srec[tl][256 * (b + 1)];
        for (int m = 0; m < 16; m++)
            d[n * 16 + ((n - m) & 15)] = K[m * 16 + n];
    }
    __syncthreads();
    // coalesced stream-out
    float4* gdst = (float4*)(ws + 1024 + (size_t)t_base * RECF);
    const float4* lsrc = (const float4*)&srec[0][0];
    for (int i = tid; i < 8 * RECF / 4; i += 128) gdst[i] = lsrc[i];
}

// ---------------------------------------------------------------------------
// Kernel 3: walker v9. Identical math to v6 (round-4 verified: 4 independent
// chains per wave, DPP row_ror dots, all gates lane-local). Depth-3 slot
// pipeline uses PLAIN HIP loads; issue order is pinned with sched_barrier(0)
// after each load batch, so the compiler's automatic waitcnt insertion emits
// the counted vmcnt wait. No inline-asm memory ops anywhere.
// ---------------------------------------------------------------------------
struct Slot {
    float4 A0, A1, A2, A3;  // A (diag-packed row n)
    float4 B0, B1, B2, B3;  // K1^T (r gate)
    float4 Z0, Z1, Z2, Z3;  // K3^T (z gate)
    float4 C0, C1, C2, C3;  // K5^T (candidate)
    float4 ex;              // {bh, uR, uZ, u4}
};

__device__ __forceinline__ void load_slot(Slot& S, const char* __restrict__ recb8, int t,
                                          unsigned offA, unsigned offX) {
    const char* r = recb8 + (size_t)t * RECB;
    S.A0 = *(const float4*)(r + offA);
    S.A1 = *(const float4*)(r + offA + 16);
    S.A2 = *(const float4*)(r + offA + 32);
    S.A3 = *(const float4*)(r + offA + 48);
    S.B0 = *(const float4*)(r + offA + 1024);
    S.B1 = *(const float4*)(r + offA + 1040);
    S.B2 = *(const float4*)(r + offA + 1056);
    S.B3 = *(const float4*)(r + offA + 1072);
    S.Z0 = *(const float4*)(r + offA + 2048);
    S.Z1 = *(const float4*)(r + offA + 2064);
    S.Z2 = *(const float4*)(r + offA + 2080);
    S.Z3 = *(const float4*)(r + offA + 2096);
    S.C0 = *(const float4*)(r + offA + 3072);
    S.C1 = *(const float4*)(r + offA + 3088);
    S.C2 = *(const float4*)(r + offA + 3104);
    S.C3 = *(const float4*)(r + offA + 3120);
    S.ex = *(const float4*)(r + offX);
}

__device__ __forceinline__ void rot16(float v, float rr[16]) {
    rr[0] = v;
    rr[1] = ROR(v, 1);
    rr[2] = ROR(v, 2);
    rr[3] = ROR(v, 3);
    rr[4] = ROR(v, 4);
    rr[5] = ROR(v, 5);
    rr[6] = ROR(v, 6);
    rr[7] = ROR(v, 7);
    rr[8] = ROR(v, 8);
    rr[9] = ROR(v, 9);
    rr[10] = ROR(v, 10);
    rr[11] = ROR(v, 11);
    rr[12] = ROR(v, 12);
    rr[13] = ROR(v, 13);
    rr[14] = ROR(v, 14);
    rr[15] = ROR(v, 15);
}

__device__ __forceinline__ float dotw(const float4& w0, const float4& w1, const float4& w2,
                                      const float4& w3, const float rr[16]) {
    float a0 = w0.x * rr[0];
    float a1 = w0.y * rr[1];
    float a2 = w0.z * rr[2];
    float a3 = w0.w * rr[3];
    a0 = fmaf(w1.x, rr[4], a0);
    a1 = fmaf(w1.y, rr[5], a1);
    a2 = fmaf(w1.z, rr[6], a2);
    a3 = fmaf(w1.w, rr[7], a3);
    a0 = fmaf(w2.x, rr[8], a0);
    a1 = fmaf(w2.y, rr[9], a1);
    a2 = fmaf(w2.z, rr[10], a2);
    a3 = fmaf(w2.w, rr[11], a3);
    a0 = fmaf(w3.x, rr[12], a0);
    a1 = fmaf(w3.y, rr[13], a1);
    a2 = fmaf(w3.z, rr[14], a2);
    a3 = fmaf(w3.w, rr[15], a3);
    return (a0 + a1) + (a2 + a3);
}

__device__ __forceinline__ float wstep6(const Slot& S, float hv, int t, int t0, int n,
                                        float* __restrict__ out) {
    float hh[16];
    rot16(hv, hh);
    float hg = fmaxf(dotw(S.A0, S.A1, S.A2, S.A3, hh) + S.ex.x, 0.f);
    float hgr[16];
    rot16(hg, hgr);
    float r = fsig(dotw(S.B0, S.B1, S.B2, S.B3, hgr) + S.ex.y);
    float z = fsig(dotw(S.Z0, S.Z1, S.Z2, S.Z3, hgr) + S.ex.z);
    float rg[16];
    rot16(r * hg, rg);
    float hc = ftanh(dotw(S.C0, S.C1, S.C2, S.C3, rg) + S.ex.w);
    float hn = fmaf(z, hg - hc, hc);  // h' = hc + z*(hg - hc), all lane-local
    if ((unsigned)(t - t0) < (unsigned)CHUNK) out[(size_t)t * 16 + n] = hn;
    return hn;
}

__global__ __launch_bounds__(64, 1) void k_walk9(const float* __restrict__ ws,
                                                 float* __restrict__ out) {
    const char* recb8 = (const char*)(ws + 1024);
    int lane = threadIdx.x;
    int n = lane & 15;
    int row = lane >> 4;  // chain within wave (0..3), one per DPP row

    unsigned offA = n * 64;
    unsigned offX = 4096 + n * 16;

    // XCD grouping: 128 blocks; blocks with equal (b&7) land on one XCD and get
    // consecutive logical indices so overlapping warm windows share that L2.
    int b = blockIdx.x;
    int L = (b & 7) * 16 + (b >> 3);
    int t0 = (L * 4 + row) * CHUNK;  // this row's chunk start
    int ts = t0 - W_WARM;
    if (ts < 0) ts = 0;
    int tend = t0 + CHUNK - 1;

    float hv = 0.f;

    Slot R0, R1, R2;
    load_slot(R0, recb8, ts + 0, offA, offX);
    __builtin_amdgcn_sched_barrier(0);
    load_slot(R1, recb8, ts + 1, offA, offX);
    __builtin_amdgcn_sched_barrier(0);
    load_slot(R2, recb8, ts + 2, offA, offX);
    __builtin_amdgcn_sched_barrier(0);

    for (int s = 0; s < NSTEP; s += 3) {
        int t = ts + s;
        int tl;
        hv = wstep6(R0, hv, t + 0, t0, n, out);
        tl = t + 3;
        if (tl > tend) tl = tend;
        load_slot(R0, recb8, tl, offA, offX);
        __builtin_amdgcn_sched_barrier(0);
        hv = wstep6(R1, hv, t + 1, t0, n, out);
        tl = t + 4;
        if (tl > tend) tl = tend;
        load_slot(R1, recb8, tl, offA, offX);
        __builtin_amdgcn_sched_barrier(0);
        hv = wstep6(R2, hv, t + 2, t0, n, out);
        tl = t + 5;
        if (tl > tend) tl = tend;
        load_slot(R2, recb8, tl, offA, offX);
        __builtin_amdgcn_sched_barrier(0);
    }
}

// ---------------------------------------------------------------------------
// Fallback (compact records) if ws is too small
// ---------------------------------------------------------------------------
__global__ void k_prep_c(const float* __restrict__ inp, const float* __restrict__ wx_,
                         const float* __restrict__ bx_, const float* __restrict__ wh_,
                         const float* __restrict__ bh_, const float* __restrict__ gk,
                         const float* __restrict__ gb, float* __restrict__ ws) {
    __shared__ float sfix[1024];
    __shared__ float sxg[16][16];
    int tid = threadIdx.x;
    for (int idx = tid; idx < 1024; idx += 256) sfix[idx] = ws[idx];
    int tl = tid >> 4, n = tid & 15;
    int t = blockIdx.x * 16 + tl;
    __syncthreads();
    float* rec = ws + 1024 + (size_t)t * 320;
    bool z0 = (t == 0);
    const float* wh = wh_ + t * 13;
    float w0 = wh[0];
    float aI = wh[10], aL = wh[11] * w0;
    float wc = wh[12] * w0;
    float c0 = wc * w0, c1 = wc * wh[1], c2 = wc * wh[2];
    for (int m = 0; m < 16; m++) {
        float Av = aL * sfix[n * 16 + m] + c0 * sfix[256 + n * 16 + m] +
                   c1 * sfix[512 + n * 16 + m] + c2 * sfix[768 + n * 16 + m];
        if (m == n) Av += aI;
        rec[n * 16 + m] = z0 ? 0.f : Av;
    }
    float acc = bx_[t * 16 + n];
    for (int c = 0; c < 2; c++) {
        const float* wx = wx_ + t * 26 + c * 13;
        float yL = 0.f, y0 = 0.f, y1 = 0.f, y2 = 0.f;
        for (int m = 0; m < 16; m++) {
            float xm = inp[t * 32 + m * 2 + c];
            yL += sfix[n * 16 + m] * xm;
            y0 += sfix[256 + n * 16 + m] * xm;
            y1 += sfix[512 + n * 16 + m] * xm;
            y2 += sfix[768 + n * 16 + m] * xm;
        }
        float xn = inp[t * 32 + n * 2 + c];
        float b0 = wx[12] * wx[0];
        acc += wx[10] * xn + wx[11] * wx[0] * yL + b0 * (wx[0] * y0 + wx[1] * y1 + wx[2] * y2);
    }
    float xg = fmaxf(acc, 0.f);
    sxg[tl][n] = xg;
    __syncthreads();
    const float* Kb = gk + (size_t)t * 1536;
    const float* gbt = gb + (size_t)t * 96;
    for (int qq = 0; qq < 3; qq++) {
        const float* K = Kb + (2 * qq) * 256;
        float u = gbt[2 * qq * 16 + n] + gbt[(2 * qq + 1) * 16 + n];
        for (int m = 0; m < 16; m++) u += sxg[tl][m] * K[m * 16 + n];
        rec[256 + qq * 16 + n] = u;
    }
    rec[304 + n] = z0 ? 0.f : bh_[t * 16 + n];
}

struct RegsC {
    float WA[16], WB[16], WC[16];
    float uRZ, u4, bh;
};

__device__ __forceinline__ void load_step_c(const float* __restrict__ recb,
                                            const float* __restrict__ gk, int t, int n, int q,
                                            RegsC& R) {
    const float* rb = recb + (size_t)t * 320;
#pragma unroll
    for (int k = 0; k < 4; k++) ((float4*)R.WA)[k] = ((const float4*)(rb + n * 16))[k];
    const float* kb = gk + (size_t)t * 1536 + (1 + 2 * (q & 1)) * 256 + n;
    const float* kc = gk + (size_t)t * 1536 + 5 * 256 + n;
#pragma unroll
    for (int m = 0; m < 16; m++) {
        R.WB[m] = kb[m * 16];
        R.WC[m] = kc[m * 16];
    }
    R.uRZ = rb[256 + (q & 1) * 16 + n];
    R.u4 = rb[288 + n];
    R.bh = rb[304 + n];
}

__device__ __forceinline__ void wstep_c(const RegsC& R, float hs[16], int t, int t0, int lane,
                                        int n, float* __restrict__ out) {
    float a0 = 0.f, a1 = 0.f, a2 = 0.f, a3 = 0.f;
#pragma unroll
    for (int m = 0; m < 16; m += 4) {
        a0 = fmaf(R.WA[m + 0], hs[m + 0], a0);
        a1 = fmaf(R.WA[m + 1], hs[m + 1], a1);
        a2 = fmaf(R.WA[m + 2], hs[m + 2], a2);
        a3 = fmaf(R.WA[m + 3], hs[m + 3], a3);
    }
    float hg = fmaxf((a0 + a1) + (a2 + a3) + R.bh, 0.f);
    float hgs[16];
#pragma unroll
    for (int m = 0; m < 16; m++) hgs[m] = RL(hg, m);
    a0 = a1 = a2 = a3 = 0.f;
#pragma unroll
    for (int m = 0; m < 16; m += 4) {
        a0 = fmaf(R.WB[m + 0], hgs[m + 0], a0);
        a1 = fmaf(R.WB[m + 1], hgs[m + 1], a1);
        a2 = fmaf(R.WB[m + 2], hgs[m + 2], a2);
        a3 = fmaf(R.WB[m + 3], hgs[m + 3], a3);
    }
    float rz = fsig((a0 + a1) + (a2 + a3) + R.uRZ);
    float zsw = __shfl_xor(rz, 16);
    float rhg = rz * hg;
    float rhgs[16];
#pragma unroll
    for (int m = 0; m < 16; m++) rhgs[m] = RL(rhg, m);
    a0 = a1 = a2 = a3 = 0.f;
#pragma unroll
    for (int m = 0; m < 16; m += 4) {
        a0 = fmaf(R.WC[m + 0], rhgs[m + 0], a0);
        a1 = fmaf(R.WC[m + 1], rhgs[m + 1], a1);
        a2 = fmaf(R.WC[m + 2], rhgs[m + 2], a2);
        a3 = fmaf(R.WC[m + 3], rhgs[m + 3], a3);
    }
    float hc = ftanh((a0 + a1) + (a2 + a3) + R.u4);
    float h = fmaf(zsw, hg - hc, hc);
    if (t >= t0 && lane < 16) out[(size_t)t * 16 + n] = h;
#pragma unroll
    for (int m = 0; m < 16; m++) hs[m] = RL(h, m);
}

__global__ __launch_bounds__(64) void k_walk_c(const float* __restrict__ ws,
                                               const float* __restrict__ gk,
                                               float* __restrict__ out) {
    const float* recb = ws + 1024;
    int lane = threadIdx.x;
    int n = lane & 15;
    int q = lane >> 4;
    int t0 = blockIdx.x * 64;
    int te = t0 + 64;
    int ts = t0 - W_WARM;
    if (ts < 0) ts = 0;
    RegsC Ra, Rb;
    load_step_c(recb, gk, ts, n, q, Ra);
    load_step_c(recb, gk, ts + 1, n, q, Rb);
    float hs[16];
#pragma unroll
    for (int m = 0; m < 16; m++) hs[m] = 0.f;
    for (int t = ts; t < te; t += 2) {
        wstep_c(Ra, hs, t, t0, lane, n, out);
        int tn = t + 2;
        load_step_c(recb, gk, tn < TT ? tn : TT - 1, n, q, Ra);
        wstep_c(Rb, hs, t + 1, t0, lane, n, out);
        int tm = t + 3;
        load_step_c(recb, gk, tm < TT ? tm : TT - 1, n, q, Rb);
    }
}

// ---------------------------------------------------------------------------
extern "C" void kernel_launch(void* const* d_in, const int* in_sizes, int n_in, void* d_out,
                              int out_size, void* d_ws, size_t ws_size, hipStream_t stream) {
    const float* inp = (const float*)d_in[0];
    const float* a = (const float*)d_in[1];
    const float* wx = (const float*)d_in[2];
    const float* bx = (const float*)d_in[3];
    const float* wh = (const float*)d_in[4];
    const float* bh = (const float*)d_in[5];
    const float* gk = (const float*)d_in[6];
    const float* gb = (const float*)d_in[7];
    float* out = (float*)d_out;
    float* ws = (float*)d_ws;

    size_t need = 4ull * (1024ull + (size_t)TT * RECF);  // ~71.3 MB
    k_fixed<<<dim3(1), dim3(256), 0, stream>>>(a, ws);
    if (ws_size >= need) {
        k_prep3<<<dim3(TT / 8), dim3(128), 0, stream>>>(inp, wx, bx, wh, bh, gk, gb, ws);
        k_walk9<<<dim3(TT / (4 * CHUNK)), dim3(64), 0, stream>>>(ws, out);
    } else {
        k_prep_c<<<dim3(TT / 16), dim3(256), 0, stream>>>(inp, wx, bx, wh, bh, gk, gb, ws);
        k_walk_c<<<dim3(TT / 64), dim3(64), 0, stream>>>(ws, gk, out);
    }
}